// Round 1
// baseline (4667.953 us; speedup 1.0000x reference)
//
#include <hip/hip_runtime.h>
#include <hip/hip_fp16.h>

// ---------------------------------------------------------------------------
// Problem constants
// ---------------------------------------------------------------------------
#define BB 512
#define TT 128
#define DD 1024
#define HH 1024
#define VV 256
#define SS 26

typedef _Float16 half8 __attribute__((ext_vector_type(8)));
typedef float f32x4 __attribute__((ext_vector_type(4)));

// ---------------------------------------------------------------------------
// fast device math (target accuracy ~1e-6, plenty for 6.25e-3 threshold)
// ---------------------------------------------------------------------------
__device__ __forceinline__ float tanh_fast(float x) {
    float ex = __expf(2.f * x);
    return 1.f - 2.f * __builtin_amdgcn_rcpf(ex + 1.f);
}
__device__ __forceinline__ float sigmoid_fast(float x) {
    return __builtin_amdgcn_rcpf(1.f + __expf(-x));
}

// ---------------------------------------------------------------------------
// f32 -> f16 conversion (grid-stride)
// ---------------------------------------------------------------------------
__global__ void cvt_f32_to_f16(const float* __restrict__ src,
                               _Float16* __restrict__ dst, long n) {
    long i = (long)blockIdx.x * blockDim.x + threadIdx.x;
    long stride = (long)gridDim.x * blockDim.x;
    for (; i < n; i += stride) dst[i] = (_Float16)src[i];
}

// wcat[g][0:1024] = W_ih[g][0:1024]; wcat[g][1024:2048] = W_hh[g][0:1024]
__global__ void build_wcat(const float* __restrict__ W_ih,
                           const float* __restrict__ W_hh,
                           _Float16* __restrict__ wcat) {
    int idx = blockIdx.x * 256 + threadIdx.x;   // 4096*2048 total
    int g = idx >> 11;
    int k = idx & 2047;
    float v = (k < 1024) ? W_ih[(size_t)g * 1280 + k]
                         : W_hh[(size_t)g * 1024 + (k - 1024)];
    wcat[idx] = (_Float16)v;
}

// onehT[v][g] = W_ih[g][1024+v]   (fp32: feeds LSTM directly, keep precision)
__global__ void build_onehT(const float* __restrict__ W_ih,
                            float* __restrict__ onehT) {
    int idx = blockIdx.x * 256 + threadIdx.x;   // 256*4096 total
    int v = idx >> 12;
    int g = idx & 4095;
    onehT[idx] = W_ih[(size_t)g * 1280 + 1024 + v];
}

// ---------------------------------------------------------------------------
// GEMM: C[M,N] = A[M,K] * B[N,K]^T  (+bias[n])
// fp16 inputs, fp32 accumulate. 128x128 block tile, BK=32, 4 waves (2x2),
// each wave 64x64 via 4x4 grid of 16x16x32 MFMAs.
// MODE 0: f32 out (ldc).  MODE 1: f16 out (ldc).
// MODE 2: logits remap: row m -> (s=m/512, b=m%512), out[(b*26+s)*256+n] f32.
// Requires: M%128==0, N%128==0, K%32==0, 16B-aligned pointers.
// ---------------------------------------------------------------------------
template <int MODE>
__global__ __launch_bounds__(256) void gemm_bt(
    const _Float16* __restrict__ A, int lda,
    const _Float16* __restrict__ B, int ldb,
    void* __restrict__ Cp, int ldc,
    int M, int N, int K, const float* __restrict__ bias) {
    __shared__ __align__(16) _Float16 As[128 * 32];
    __shared__ __align__(16) _Float16 Bs[128 * 32];

    const int tid  = threadIdx.x;
    const int lane = tid & 63;
    const int wid  = tid >> 6;
    const int wm   = wid >> 1;   // 0..1
    const int wn   = wid & 1;    // 0..1
    const int m0 = blockIdx.y * 128;
    const int n0 = blockIdx.x * 128;

    f32x4 acc[4][4];
#pragma unroll
    for (int i = 0; i < 4; ++i)
#pragma unroll
        for (int j = 0; j < 4; ++j) {
            acc[i][j][0] = 0.f; acc[i][j][1] = 0.f;
            acc[i][j][2] = 0.f; acc[i][j][3] = 0.f;
        }

    // staging: each thread moves two 16B chunks per tile (rows 0..63 / 64..127)
    const int row0 = tid >> 2;          // 0..63
    const int ch0  = tid & 3;           // 16B chunk within a 64B row
    const _Float16* a0 = A + (size_t)(m0 + row0) * lda + ch0 * 8;
    const _Float16* a1 = A + (size_t)(m0 + row0 + 64) * lda + ch0 * 8;
    const _Float16* b0 = B + (size_t)(n0 + row0) * ldb + ch0 * 8;
    const _Float16* b1 = B + (size_t)(n0 + row0 + 64) * ldb + ch0 * 8;
    _Float16* sa0 = As + row0 * 32 + ch0 * 8;
    _Float16* sa1 = As + (row0 + 64) * 32 + ch0 * 8;
    _Float16* sb0 = Bs + row0 * 32 + ch0 * 8;
    _Float16* sb1 = Bs + (row0 + 64) * 32 + ch0 * 8;

    const int la = lane & 15;
    const int kc = (lane >> 4) * 8;

    for (int k0 = 0; k0 < K; k0 += 32) {
        uint4 va0 = *(const uint4*)(a0 + k0);
        uint4 va1 = *(const uint4*)(a1 + k0);
        uint4 vb0 = *(const uint4*)(b0 + k0);
        uint4 vb1 = *(const uint4*)(b1 + k0);
        __syncthreads();
        *(uint4*)sa0 = va0;
        *(uint4*)sa1 = va1;
        *(uint4*)sb0 = vb0;
        *(uint4*)sb1 = vb1;
        __syncthreads();

        half8 af[4], bf[4];
#pragma unroll
        for (int mt = 0; mt < 4; ++mt) {
            int r = wm * 64 + mt * 16 + la;
            af[mt] = *(const half8*)(As + r * 32 + kc);
        }
#pragma unroll
        for (int nt = 0; nt < 4; ++nt) {
            int r = wn * 64 + nt * 16 + la;
            bf[nt] = *(const half8*)(Bs + r * 32 + kc);
        }
#pragma unroll
        for (int mt = 0; mt < 4; ++mt)
#pragma unroll
            for (int nt = 0; nt < 4; ++nt)
                acc[mt][nt] = __builtin_amdgcn_mfma_f32_16x16x32_f16(
                    af[mt], bf[nt], acc[mt][nt], 0, 0, 0);
    }

    // epilogue: C/D layout col = lane&15, row = (lane>>4)*4 + reg
#pragma unroll
    for (int mt = 0; mt < 4; ++mt) {
#pragma unroll
        for (int nt = 0; nt < 4; ++nt) {
            int gn = n0 + wn * 64 + nt * 16 + la;
            float bv = bias ? bias[gn] : 0.f;
#pragma unroll
            for (int r = 0; r < 4; ++r) {
                int gm = m0 + wm * 64 + mt * 16 + (lane >> 4) * 4 + r;
                float v = acc[mt][nt][r] + bv;
                if (MODE == 0) {
                    ((float*)Cp)[(size_t)gm * ldc + gn] = v;
                } else if (MODE == 1) {
                    ((_Float16*)Cp)[(size_t)gm * ldc + gn] = (_Float16)v;
                } else {
                    int s = gm >> 9;
                    int b = gm & 511;
                    ((float*)Cp)[((size_t)b * SS + s) * VV + gn] = v;
                }
            }
        }
    }
}

// ---------------------------------------------------------------------------
// Fused Bahdanau attention, one block per batch row b.
//   e[t]   = sum_h sw[h] * tanh(pH[b,t,h] + ph[b,h])
//   alpha  = softmax(e)
//   ctx[d] = sum_t alpha[t] * bh[b,t,d]   -> acat[b][0:1024] (f16)
// ---------------------------------------------------------------------------
__global__ __launch_bounds__(256) void attn_kernel(
    const _Float16* __restrict__ pH,   // [B,T,H]
    const _Float16* __restrict__ bh,   // [B,T,D]
    const float* __restrict__ ph,      // [B,H]
    const float* __restrict__ sw,      // [H]
    _Float16* __restrict__ acat) {     // [B,2048]
    __shared__ float sw_s[HH];
    __shared__ float ph_s[HH];
    __shared__ float e_s[TT];
    __shared__ float al_s[TT];

    const int b = blockIdx.x;
    const int tid = threadIdx.x;
    const int lane = tid & 63;
    const int wv = tid >> 6;

    for (int i = tid; i < HH; i += 256) {
        sw_s[i] = sw[i];
        ph_s[i] = ph[(size_t)b * HH + i];
    }
    __syncthreads();

    // phase A: wave wv handles t = wv*32 .. wv*32+31
    const _Float16* pHb = pH + (size_t)b * TT * HH;
    for (int tt = 0; tt < 32; ++tt) {
        int t = wv * 32 + tt;
        const _Float16* prow = pHb + (size_t)t * HH;
        float acc = 0.f;
#pragma unroll
        for (int k = 0; k < 16; ++k) {
            int hh = lane + 64 * k;
            float x = (float)prow[hh] + ph_s[hh];
            acc += tanh_fast(x) * sw_s[hh];
        }
#pragma unroll
        for (int off = 32; off > 0; off >>= 1) acc += __shfl_xor(acc, off, 64);
        if (lane == 0) e_s[t] = acc;
    }
    __syncthreads();

    // phase B: softmax over 128 scores (threads 0..127)
    if (tid < TT) {
        float m = -1e30f;
        for (int t = 0; t < TT; ++t) m = fmaxf(m, e_s[t]);
        float s = 0.f;
        for (int t = 0; t < TT; ++t) s += __expf(e_s[t] - m);
        al_s[tid] = __expf(e_s[tid] - m) / s;
    }
    __syncthreads();

    // phase C: context accumulation; thread j owns cols {j, j+256, j+512, j+768}
    const _Float16* bhb = bh + (size_t)b * TT * DD;
    float cx0 = 0.f, cx1 = 0.f, cx2 = 0.f, cx3 = 0.f;
    for (int t = 0; t < TT; ++t) {
        float a = al_s[t];
        const _Float16* row = bhb + (size_t)t * DD;
        cx0 += a * (float)row[tid];
        cx1 += a * (float)row[tid + 256];
        cx2 += a * (float)row[tid + 512];
        cx3 += a * (float)row[tid + 768];
    }
    _Float16* dst = acat + (size_t)b * 2048;
    dst[tid]       = (_Float16)cx0;
    dst[tid + 256] = (_Float16)cx1;
    dst[tid + 512] = (_Float16)cx2;
    dst[tid + 768] = (_Float16)cx3;
}

// ---------------------------------------------------------------------------
// LSTM pointwise: gates [B,4096] (no bias yet) + biases + one-hot column.
// Torch gate order i,f,g,o. Writes c (f32), h (f16) into acat[:,1024:2048]
// and hid[step].
// ---------------------------------------------------------------------------
__global__ __launch_bounds__(256) void lstm_kernel(
    const float* __restrict__ gates,   // [B,4H]
    const float* __restrict__ b_ih,    // [4H]
    const float* __restrict__ b_hh,    // [4H]
    const float* __restrict__ onehT,   // [V,4H]
    const int* __restrict__ text,      // [B,SS]
    int step,
    float* __restrict__ c,             // [B,H]
    _Float16* __restrict__ acat,       // [B,2048]
    _Float16* __restrict__ hid) {      // [SS,B,H]
    int idx = blockIdx.x * 256 + threadIdx.x;  // B*H
    int b = idx >> 10;
    int j = idx & 1023;
    int tok = text[b * SS + step];
    const float* grow = gates + (size_t)b * 4096;
    const float* orow = onehT + (size_t)tok * 4096;

    float ig = grow[j]        + b_ih[j]        + b_hh[j]        + orow[j];
    float fg = grow[1024 + j] + b_ih[1024 + j] + b_hh[1024 + j] + orow[1024 + j];
    float gg = grow[2048 + j] + b_ih[2048 + j] + b_hh[2048 + j] + orow[2048 + j];
    float og = grow[3072 + j] + b_ih[3072 + j] + b_hh[3072 + j] + orow[3072 + j];

    float cn = sigmoid_fast(fg) * c[idx] + sigmoid_fast(ig) * tanh_fast(gg);
    float hn = sigmoid_fast(og) * tanh_fast(cn);
    c[idx] = cn;
    _Float16 h16 = (_Float16)hn;
    acat[(size_t)b * 2048 + 1024 + j] = h16;
    hid[((size_t)step * BB + b) * HH + j] = h16;
}

// ---------------------------------------------------------------------------
// host
// ---------------------------------------------------------------------------
extern "C" void kernel_launch(void* const* d_in, const int* in_sizes, int n_in,
                              void* d_out, int out_size, void* d_ws, size_t ws_size,
                              hipStream_t stream) {
    const float* batch_H = (const float*)d_in[0];
    const int*   text    = (const int*)d_in[1];
    const float* i2h_w   = (const float*)d_in[2];
    const float* h2h_w   = (const float*)d_in[3];
    const float* h2h_b   = (const float*)d_in[4];
    const float* score_w = (const float*)d_in[5];
    const float* W_ih    = (const float*)d_in[6];
    const float* W_hh    = (const float*)d_in[7];
    const float* b_ih    = (const float*)d_in[8];
    const float* b_hh    = (const float*)d_in[9];
    const float* gen_w   = (const float*)d_in[10];
    const float* gen_b   = (const float*)d_in[11];
    float* out = (float*)d_out;

    // workspace carve-up (256B aligned)
    char* ws = (char*)d_ws;
    size_t off = 0;
    auto carve = [&](size_t bytes) -> void* {
        void* p = ws + off;
        off += (bytes + 255) & ~(size_t)255;
        return p;
    };
    _Float16* bh16   = (_Float16*)carve((size_t)BB * TT * DD * 2);   // 128 MiB
    _Float16* pH16   = (_Float16*)carve((size_t)BB * TT * HH * 2);   // 128 MiB
    _Float16* wi2h16 = (_Float16*)carve((size_t)HH * DD * 2);
    _Float16* wh2h16 = (_Float16*)carve((size_t)HH * HH * 2);
    _Float16* wcat16 = (_Float16*)carve((size_t)4 * HH * 2048 * 2);  // 16 MiB
    _Float16* wgen16 = (_Float16*)carve((size_t)VV * HH * 2);
    float*    onehT  = (float*)carve((size_t)VV * 4 * HH * 4);       // 4 MiB
    _Float16* acat   = (_Float16*)carve((size_t)BB * 2048 * 2);      // [ctx|h]
    float*    ph_f   = (float*)carve((size_t)BB * HH * 4);
    float*    gates  = (float*)carve((size_t)BB * 4 * HH * 4);       // 8 MiB
    float*    c_f    = (float*)carve((size_t)BB * HH * 4);
    _Float16* hid16  = (_Float16*)carve((size_t)SS * BB * HH * 2);   // 26 MiB

    const dim3 blk(256);

    // --- precompute: conversions + tables ---
    {
        long n = (long)BB * TT * DD;
        cvt_f32_to_f16<<<dim3(65536), blk, 0, stream>>>(batch_H, bh16, n);
        cvt_f32_to_f16<<<dim3(4096), blk, 0, stream>>>(i2h_w, wi2h16, (long)HH * DD);
        cvt_f32_to_f16<<<dim3(4096), blk, 0, stream>>>(h2h_w, wh2h16, (long)HH * HH);
        cvt_f32_to_f16<<<dim3(1024), blk, 0, stream>>>(gen_w, wgen16, (long)VV * HH);
        build_wcat<<<dim3(4 * HH * 2048 / 256), blk, 0, stream>>>(W_ih, W_hh, wcat16);
        build_onehT<<<dim3(VV * 4 * HH / 256), blk, 0, stream>>>(W_ih, onehT);
        hipMemsetAsync(acat, 0, (size_t)BB * 2048 * 2, stream);  // h0 = 0 (and ctx half)
        hipMemsetAsync(c_f, 0, (size_t)BB * HH * 4, stream);     // c0 = 0
    }

    // --- proj_H = batch_H @ i2h_w^T : [65536,1024] x [1024,1024]^T -> f16 ---
    gemm_bt<1><<<dim3(HH / 128, BB * TT / 128), blk, 0, stream>>>(
        bh16, DD, wi2h16, DD, pH16, HH, BB * TT, HH, DD, nullptr);

    // --- recurrent steps ---
    for (int s = 0; s < SS; ++s) {
        // proj_h = h @ h2h_w^T + h2h_b : A = acat[:,1024:2048] (lda=2048)
        gemm_bt<0><<<dim3(HH / 128, BB / 128), blk, 0, stream>>>(
            acat + 1024, 2048, wh2h16, HH, ph_f, HH, BB, HH, HH, h2h_b);

        attn_kernel<<<dim3(BB), blk, 0, stream>>>(pH16, bh16, ph_f, score_w, acat);

        // gates = [ctx|h] @ [W_ih[:,:D]|W_hh]^T : [512,2048] x [4096,2048]^T
        gemm_bt<0><<<dim3(4 * HH / 128, BB / 128), blk, 0, stream>>>(
            acat, 2048, wcat16, 2048, gates, 4 * HH, BB, 4 * HH, 2048, nullptr);

        lstm_kernel<<<dim3(BB * HH / 256), blk, 0, stream>>>(
            gates, b_ih, b_hh, onehT, text, s, c_f, acat, hid16);
    }

    // --- logits = hid @ gen_w^T + gen_b, remapped [s,b,v] -> [b,s,v] ---
    gemm_bt<2><<<dim3(VV / 128, SS * BB / 128), blk, 0, stream>>>(
        hid16, HH, wgen16, HH, out, VV, SS * BB, VV, HH, gen_b);
}

// Round 2
// 3919.884 us; speedup vs baseline: 1.1908x; 1.1908x over previous
//
#include <hip/hip_runtime.h>
#include <hip/hip_fp16.h>

// ---------------------------------------------------------------------------
// Problem constants
// ---------------------------------------------------------------------------
#define BB 512
#define TT 128
#define DD 1024
#define HH 1024
#define VV 256
#define SS 26

typedef _Float16 half8 __attribute__((ext_vector_type(8)));
typedef _Float16 half4 __attribute__((ext_vector_type(4)));
typedef float f32x4 __attribute__((ext_vector_type(4)));

// ---------------------------------------------------------------------------
// fast device math
// ---------------------------------------------------------------------------
__device__ __forceinline__ float tanh_fast(float x) {
    float ex = __expf(2.f * x);
    return 1.f - 2.f * __builtin_amdgcn_rcpf(ex + 1.f);
}
__device__ __forceinline__ float sigmoid_fast(float x) {
    return __builtin_amdgcn_rcpf(1.f + __expf(-x));
}

// ---------------------------------------------------------------------------
// f32 -> f16 conversion, 4 elements/thread (n % 4 == 0)
// ---------------------------------------------------------------------------
__global__ void cvt_f32_to_f16_v4(const float* __restrict__ src,
                                  _Float16* __restrict__ dst, long n4) {
    long i = (long)blockIdx.x * blockDim.x + threadIdx.x;
    long stride = (long)gridDim.x * blockDim.x;
    for (; i < n4; i += stride) {
        float4 v = ((const float4*)src)[i];
        half4 h;
        h[0] = (_Float16)v.x; h[1] = (_Float16)v.y;
        h[2] = (_Float16)v.z; h[3] = (_Float16)v.w;
        ((half4*)dst)[i] = h;
    }
}

// Gate-interleaved concatenated LSTM weight:
// col c in [0,4096): jgroup g=c>>6, gate q=(c>>4)&3, jl=c&15 -> orig row q*1024+g*16+jl
// k in [0,2048): k<1024 -> W_ih[row][k] (row stride 1280), else W_hh[row][k-1024]
__global__ void build_wcatp(const float* __restrict__ W_ih,
                            const float* __restrict__ W_hh,
                            _Float16* __restrict__ wcatp) {
    int idx = blockIdx.x * 256 + threadIdx.x;   // 4096*2048 total
    int c = idx >> 11;
    int k = idx & 2047;
    int g = c >> 6, q = (c >> 4) & 3, jl = c & 15;
    int row = q * 1024 + g * 16 + jl;
    float v = (k < 1024) ? W_ih[(size_t)row * 1280 + k]
                         : W_hh[(size_t)row * 1024 + (k - 1024)];
    wcatp[idx] = (_Float16)v;
}

// onehT[v][g] = W_ih[g][1024+v]   (fp32, original gate-major order)
__global__ void build_onehT(const float* __restrict__ W_ih,
                            float* __restrict__ onehT) {
    int idx = blockIdx.x * 256 + threadIdx.x;   // 256*4096 total
    int v = idx >> 12;
    int g = idx & 4095;
    onehT[idx] = W_ih[(size_t)g * 1280 + 1024 + v];
}

// bsum = b_ih + b_hh (4096)
__global__ void build_bsum(const float* __restrict__ b_ih,
                           const float* __restrict__ b_hh,
                           float* __restrict__ bsum) {
    int i = blockIdx.x * 256 + threadIdx.x;
    bsum[i] = b_ih[i] + b_hh[i];
}

// ---------------------------------------------------------------------------
// GEMM 128x128: C[M,N] = A[M,K] * B[N,K]^T (+bias). fp16 in, fp32 acc.
// MODE 1: f16 out. MODE 2: logits remap (m -> s=m/512,b=m%512) f32 out.
// SWZ 1: XCD row-grouping swizzle (requires gridDim.y % 8 == 0).
// ---------------------------------------------------------------------------
template <int MODE, int SWZ>
__global__ __launch_bounds__(256) void gemm_bt(
    const _Float16* __restrict__ A, int lda,
    const _Float16* __restrict__ B, int ldb,
    void* __restrict__ Cp, int ldc, int K, const float* __restrict__ bias) {
    __shared__ __align__(16) _Float16 As[128 * 32];
    __shared__ __align__(16) _Float16 Bs[128 * 32];

    int bx = blockIdx.x, by = blockIdx.y;
    if (SWZ) {
        int nx = gridDim.x;
        int bid = by * nx + bx;
        int xcd = bid & 7;
        int local = bid >> 3;
        int rows_per_xcd = gridDim.y >> 3;
        bx = local % nx;
        by = xcd * rows_per_xcd + local / nx;
    }
    const int tid  = threadIdx.x;
    const int lane = tid & 63;
    const int wid  = tid >> 6;
    const int wm   = wid >> 1;
    const int wn   = wid & 1;
    const int m0 = by * 128;
    const int n0 = bx * 128;

    f32x4 acc[4][4];
#pragma unroll
    for (int i = 0; i < 4; ++i)
#pragma unroll
        for (int j = 0; j < 4; ++j)
            acc[i][j] = (f32x4){0.f, 0.f, 0.f, 0.f};

    const int row0 = tid >> 2;
    const int ch0  = tid & 3;
    const _Float16* a0 = A + (size_t)(m0 + row0) * lda + ch0 * 8;
    const _Float16* a1 = A + (size_t)(m0 + row0 + 64) * lda + ch0 * 8;
    const _Float16* b0 = B + (size_t)(n0 + row0) * ldb + ch0 * 8;
    const _Float16* b1 = B + (size_t)(n0 + row0 + 64) * ldb + ch0 * 8;
    _Float16* sa0 = As + row0 * 32 + ch0 * 8;
    _Float16* sa1 = As + (row0 + 64) * 32 + ch0 * 8;
    _Float16* sb0 = Bs + row0 * 32 + ch0 * 8;
    _Float16* sb1 = Bs + (row0 + 64) * 32 + ch0 * 8;

    const int la = lane & 15;
    const int kc = (lane >> 4) * 8;

    for (int k0 = 0; k0 < K; k0 += 32) {
        uint4 va0 = *(const uint4*)(a0 + k0);
        uint4 va1 = *(const uint4*)(a1 + k0);
        uint4 vb0 = *(const uint4*)(b0 + k0);
        uint4 vb1 = *(const uint4*)(b1 + k0);
        __syncthreads();
        *(uint4*)sa0 = va0;
        *(uint4*)sa1 = va1;
        *(uint4*)sb0 = vb0;
        *(uint4*)sb1 = vb1;
        __syncthreads();

        half8 af[4], bf[4];
#pragma unroll
        for (int mt = 0; mt < 4; ++mt)
            af[mt] = *(const half8*)(As + (wm * 64 + mt * 16 + la) * 32 + kc);
#pragma unroll
        for (int nt = 0; nt < 4; ++nt)
            bf[nt] = *(const half8*)(Bs + (wn * 64 + nt * 16 + la) * 32 + kc);
#pragma unroll
        for (int mt = 0; mt < 4; ++mt)
#pragma unroll
            for (int nt = 0; nt < 4; ++nt)
                acc[mt][nt] = __builtin_amdgcn_mfma_f32_16x16x32_f16(
                    af[mt], bf[nt], acc[mt][nt], 0, 0, 0);
    }

#pragma unroll
    for (int mt = 0; mt < 4; ++mt) {
#pragma unroll
        for (int nt = 0; nt < 4; ++nt) {
            int gn = n0 + wn * 64 + nt * 16 + la;
            float bv = bias ? bias[gn] : 0.f;
#pragma unroll
            for (int r = 0; r < 4; ++r) {
                int gm = m0 + wm * 64 + mt * 16 + (lane >> 4) * 4 + r;
                float v = acc[mt][nt][r] + bv;
                if (MODE == 1) {
                    ((_Float16*)Cp)[(size_t)gm * ldc + gn] = (_Float16)v;
                } else {
                    int s = gm >> 9;
                    int b = gm & 511;
                    ((float*)Cp)[((size_t)b * SS + s) * VV + gn] = v;
                }
            }
        }
    }
}

// ---------------------------------------------------------------------------
// GEMM 64x128 core (shared by proj_h and fused-gates kernels).
// 4 waves as 2x2; wave = 32 rows x 64 cols = acc[2][4].
// ---------------------------------------------------------------------------
#define GEMM64_CORE(A, lda, B, ldb, K)                                        \
    __shared__ __align__(16) _Float16 As[64 * 32];                            \
    __shared__ __align__(16) _Float16 Bs[128 * 32];                           \
    const int tid  = threadIdx.x;                                             \
    const int lane = tid & 63;                                                \
    const int wid  = tid >> 6;                                                \
    const int wm   = wid >> 1;                                                \
    const int wn   = wid & 1;                                                 \
    const int m0 = blockIdx.y * 64;                                           \
    const int n0 = blockIdx.x * 128;                                          \
    f32x4 acc[2][4];                                                          \
    _Pragma("unroll") for (int i = 0; i < 2; ++i)                             \
        _Pragma("unroll") for (int j = 0; j < 4; ++j)                         \
            acc[i][j] = (f32x4){0.f, 0.f, 0.f, 0.f};                          \
    const int row0 = tid >> 2;                                                \
    const int ch0  = tid & 3;                                                 \
    const _Float16* ag = A + (size_t)(m0 + row0) * lda + ch0 * 8;             \
    const _Float16* bg0 = B + (size_t)(n0 + row0) * ldb + ch0 * 8;            \
    const _Float16* bg1 = B + (size_t)(n0 + row0 + 64) * ldb + ch0 * 8;       \
    _Float16* sa  = As + row0 * 32 + ch0 * 8;                                 \
    _Float16* sb0 = Bs + row0 * 32 + ch0 * 8;                                 \
    _Float16* sb1 = Bs + (row0 + 64) * 32 + ch0 * 8;                          \
    const int la = lane & 15;                                                 \
    const int kc = (lane >> 4) * 8;                                           \
    for (int k0 = 0; k0 < K; k0 += 32) {                                      \
        uint4 va  = *(const uint4*)(ag + k0);                                 \
        uint4 vb0 = *(const uint4*)(bg0 + k0);                                \
        uint4 vb1 = *(const uint4*)(bg1 + k0);                                \
        __syncthreads();                                                      \
        *(uint4*)sa  = va;                                                    \
        *(uint4*)sb0 = vb0;                                                   \
        *(uint4*)sb1 = vb1;                                                   \
        __syncthreads();                                                      \
        half8 af[2], bf[4];                                                   \
        _Pragma("unroll") for (int mt = 0; mt < 2; ++mt)                      \
            af[mt] = *(const half8*)(As + (wm * 32 + mt * 16 + la) * 32 + kc);\
        _Pragma("unroll") for (int nt = 0; nt < 4; ++nt)                      \
            bf[nt] = *(const half8*)(Bs + (wn * 64 + nt * 16 + la) * 32 + kc);\
        _Pragma("unroll") for (int mt = 0; mt < 2; ++mt)                      \
            _Pragma("unroll") for (int nt = 0; nt < 4; ++nt)                  \
                acc[mt][nt] = __builtin_amdgcn_mfma_f32_16x16x32_f16(         \
                    af[mt], bf[nt], acc[mt][nt], 0, 0, 0);                    \
    }

// proj_h = h @ h2h^T + b : f32 out
__global__ __launch_bounds__(256) void gemm64_f32(
    const _Float16* __restrict__ A, int lda,
    const _Float16* __restrict__ B, int ldb,
    float* __restrict__ C, int ldc, int K, const float* __restrict__ bias) {
    GEMM64_CORE(A, lda, B, ldb, K)
#pragma unroll
    for (int mt = 0; mt < 2; ++mt)
#pragma unroll
        for (int nt = 0; nt < 4; ++nt) {
            int gn = n0 + wn * 64 + nt * 16 + la;
            float bv = bias[gn];
#pragma unroll
            for (int r = 0; r < 4; ++r) {
                int gm = m0 + wm * 32 + mt * 16 + (lane >> 4) * 4 + r;
                C[(size_t)gm * ldc + gn] = acc[mt][nt][r] + bv;
            }
        }
}

// gates GEMM over gate-interleaved wcatp + fused LSTM pointwise epilogue.
// B-col layout: c = g*64 + q*16 + jl  ->  gate q of j = g*16+jl.
// A lane's 4 nt-tiles are exactly gates i,f,g,o of j = (n0>>2) + wn*16 + la.
__global__ __launch_bounds__(256) void gemm_gates(
    const _Float16* __restrict__ A,      // acat [B,2048]
    const _Float16* __restrict__ B,      // wcatp [4096,2048]
    const float* __restrict__ bsum,      // [4096] gate-major
    const float* __restrict__ onehT,     // [V,4096] gate-major
    const int* __restrict__ text,        // [B,SS]
    int step,
    float* __restrict__ c,               // [B,H]
    _Float16* __restrict__ acat,         // [B,2048] (h -> cols 1024:2048)
    _Float16* __restrict__ hid) {        // [SS,B,H]
    GEMM64_CORE(A, 2048, B, 2048, 2048)
    const int quad = lane >> 4;
    const int jb = (n0 >> 2) + wn * 16 + la;
    float bs[4];
#pragma unroll
    for (int q = 0; q < 4; ++q) bs[q] = bsum[q * 1024 + jb];
#pragma unroll
    for (int mt = 0; mt < 2; ++mt) {
#pragma unroll
        for (int r = 0; r < 4; ++r) {
            int b = m0 + wm * 32 + mt * 16 + quad * 4 + r;
            int tok = text[b * SS + step];
            const float* orow = onehT + (size_t)tok * 4096;
            float ig = acc[mt][0][r] + bs[0] + orow[jb];
            float fg = acc[mt][1][r] + bs[1] + orow[1024 + jb];
            float gg = acc[mt][2][r] + bs[2] + orow[2048 + jb];
            float og = acc[mt][3][r] + bs[3] + orow[3072 + jb];
            size_t ci = (size_t)b * 1024 + jb;
            float cn = sigmoid_fast(fg) * c[ci] + sigmoid_fast(ig) * tanh_fast(gg);
            float hn = sigmoid_fast(og) * tanh_fast(cn);
            c[ci] = cn;
            _Float16 h16 = (_Float16)hn;
            acat[(size_t)b * 2048 + 1024 + jb] = h16;
            hid[((size_t)step * BB + b) * HH + jb] = h16;
        }
    }
}

// ---------------------------------------------------------------------------
// Fused Bahdanau attention, one block (256 thr) per batch row.
// Lane owns 16 contiguous h; ph/sw cached in registers; half8 loads.
// ---------------------------------------------------------------------------
__global__ __launch_bounds__(256) void attn_kernel(
    const _Float16* __restrict__ pH,   // [B,T,H]
    const _Float16* __restrict__ bh,   // [B,T,D]
    const float* __restrict__ ph,      // [B,H]
    const float* __restrict__ sw,      // [H]
    _Float16* __restrict__ acat) {     // [B,2048]
    __shared__ float e_s[TT];
    __shared__ float al_s[TT];

    const int b = blockIdx.x;
    const int tid = threadIdx.x;
    const int lane = tid & 63;
    const int wv = tid >> 6;

    // register cache of ph and sw for this lane's 16 h's
    float phr[16], swr[16];
    const float4* ph4 = (const float4*)(ph + (size_t)b * HH + lane * 16);
    const float4* sw4 = (const float4*)(sw + lane * 16);
#pragma unroll
    for (int q = 0; q < 4; ++q) {
        float4 t1 = ph4[q];
        phr[q * 4 + 0] = t1.x; phr[q * 4 + 1] = t1.y;
        phr[q * 4 + 2] = t1.z; phr[q * 4 + 3] = t1.w;
        float4 t2 = sw4[q];
        swr[q * 4 + 0] = t2.x; swr[q * 4 + 1] = t2.y;
        swr[q * 4 + 2] = t2.z; swr[q * 4 + 3] = t2.w;
    }

    // Phase A: wave wv handles t = wv*32 .. wv*32+31
    const _Float16* pHb = pH + (size_t)b * TT * HH + lane * 16;
    for (int tt = 0; tt < 32; ++tt) {
        int t = wv * 32 + tt;
        half8 p0 = *(const half8*)(pHb + (size_t)t * HH);
        half8 p1 = *(const half8*)(pHb + (size_t)t * HH + 8);
        float acc = 0.f;
#pragma unroll
        for (int k = 0; k < 8; ++k)
            acc += tanh_fast((float)p0[k] + phr[k]) * swr[k];
#pragma unroll
        for (int k = 0; k < 8; ++k)
            acc += tanh_fast((float)p1[k] + phr[8 + k]) * swr[8 + k];
#pragma unroll
        for (int off = 32; off > 0; off >>= 1) acc += __shfl_xor(acc, off, 64);
        if (lane == 0) e_s[t] = acc;
    }
    __syncthreads();

    // Phase B: softmax over 128 scores
    if (tid < TT) {
        float m = -1e30f;
        for (int t = 0; t < TT; ++t) m = fmaxf(m, e_s[t]);
        float s = 0.f;
        for (int t = 0; t < TT; ++t) s += __expf(e_s[t] - m);
        al_s[tid] = __expf(e_s[tid] - m) / s;
    }
    __syncthreads();

    // Phase C: thread owns 4 contiguous d = tid*4..tid*4+3
    const _Float16* bhb = bh + (size_t)b * TT * DD + tid * 4;
    float c0 = 0.f, c1 = 0.f, c2 = 0.f, c3 = 0.f;
#pragma unroll 4
    for (int t = 0; t < TT; ++t) {
        float a = al_s[t];
        half4 v = *(const half4*)(bhb + (size_t)t * DD);
        c0 += a * (float)v[0];
        c1 += a * (float)v[1];
        c2 += a * (float)v[2];
        c3 += a * (float)v[3];
    }
    half4 o;
    o[0] = (_Float16)c0; o[1] = (_Float16)c1;
    o[2] = (_Float16)c2; o[3] = (_Float16)c3;
    *(half4*)(acat + (size_t)b * 2048 + tid * 4) = o;
}

// ---------------------------------------------------------------------------
// host
// ---------------------------------------------------------------------------
extern "C" void kernel_launch(void* const* d_in, const int* in_sizes, int n_in,
                              void* d_out, int out_size, void* d_ws, size_t ws_size,
                              hipStream_t stream) {
    const float* batch_H = (const float*)d_in[0];
    const int*   text    = (const int*)d_in[1];
    const float* i2h_w   = (const float*)d_in[2];
    const float* h2h_w   = (const float*)d_in[3];
    const float* h2h_b   = (const float*)d_in[4];
    const float* score_w = (const float*)d_in[5];
    const float* W_ih    = (const float*)d_in[6];
    const float* W_hh    = (const float*)d_in[7];
    const float* b_ih    = (const float*)d_in[8];
    const float* b_hh    = (const float*)d_in[9];
    const float* gen_w   = (const float*)d_in[10];
    const float* gen_b   = (const float*)d_in[11];
    float* out = (float*)d_out;

    char* ws = (char*)d_ws;
    size_t off = 0;
    auto carve = [&](size_t bytes) -> void* {
        void* p = ws + off;
        off += (bytes + 255) & ~(size_t)255;
        return p;
    };
    _Float16* bh16   = (_Float16*)carve((size_t)BB * TT * DD * 2);   // 128 MiB
    _Float16* pH16   = (_Float16*)carve((size_t)BB * TT * HH * 2);   // 128 MiB
    _Float16* wi2h16 = (_Float16*)carve((size_t)HH * DD * 2);
    _Float16* wh2h16 = (_Float16*)carve((size_t)HH * HH * 2);
    _Float16* wcatp  = (_Float16*)carve((size_t)4 * HH * 2048 * 2);  // 16 MiB
    _Float16* wgen16 = (_Float16*)carve((size_t)VV * HH * 2);
    float*    onehT  = (float*)carve((size_t)VV * 4 * HH * 4);       // 4 MiB
    float*    bsum   = (float*)carve((size_t)4 * HH * 4);
    _Float16* acat   = (_Float16*)carve((size_t)BB * 2048 * 2);
    float*    ph_f   = (float*)carve((size_t)BB * HH * 4);
    float*    c_f    = (float*)carve((size_t)BB * HH * 4);
    _Float16* hid16  = (_Float16*)carve((size_t)SS * BB * HH * 2);   // 26 MiB

    const dim3 blk(256);

    cvt_f32_to_f16_v4<<<dim3(16384), blk, 0, stream>>>(batch_H, bh16, (long)BB * TT * DD / 4);
    cvt_f32_to_f16_v4<<<dim3(1024), blk, 0, stream>>>(i2h_w, wi2h16, (long)HH * DD / 4);
    cvt_f32_to_f16_v4<<<dim3(1024), blk, 0, stream>>>(h2h_w, wh2h16, (long)HH * HH / 4);
    cvt_f32_to_f16_v4<<<dim3(256), blk, 0, stream>>>(gen_w, wgen16, (long)VV * HH / 4);
    build_wcatp<<<dim3(4 * HH * 2048 / 256), blk, 0, stream>>>(W_ih, W_hh, wcatp);
    build_onehT<<<dim3(VV * 4 * HH / 256), blk, 0, stream>>>(W_ih, onehT);
    build_bsum<<<dim3(16), blk, 0, stream>>>(b_ih, b_hh, bsum);
    hipMemsetAsync(acat, 0, (size_t)BB * 2048 * 2, stream);  // h0 = 0
    hipMemsetAsync(c_f, 0, (size_t)BB * HH * 4, stream);     // c0 = 0

    // proj_H = batch_H @ i2h_w^T -> f16 [B*T, H], XCD-swizzled
    gemm_bt<1, 1><<<dim3(HH / 128, BB * TT / 128), blk, 0, stream>>>(
        bh16, DD, wi2h16, DD, pH16, HH, DD, nullptr);

    for (int s = 0; s < SS; ++s) {
        // proj_h = h @ h2h^T + h2h_b : [512,1024], grid (8,8)
        gemm64_f32<<<dim3(HH / 128, BB / 64), blk, 0, stream>>>(
            acat + 1024, 2048, wh2h16, HH, ph_f, HH, HH, h2h_b);

        attn_kernel<<<dim3(BB), blk, 0, stream>>>(pH16, bh16, ph_f, score_w, acat);

        // gates GEMM + fused LSTM: [512,2048] x [4096,2048]^T, grid (32,8)
        gemm_gates<<<dim3(4 * HH / 128, BB / 64), blk, 0, stream>>>(
            acat, wcatp, bsum, onehT, text, s, c_f, acat, hid16);
    }

    // logits = hid @ gen_w^T + gen_b, remap [s,b,v] -> [b,s,v]
    gemm_bt<2, 0><<<dim3(VV / 128, SS * BB / 128), blk, 0, stream>>>(
        hid16, HH, wgen16, HH, out, VV, HH, gen_b);
}

// Round 3
// 3582.191 us; speedup vs baseline: 1.3031x; 1.0943x over previous
//
#include <hip/hip_runtime.h>
#include <hip/hip_fp16.h>

// ---------------------------------------------------------------------------
// Problem constants
// ---------------------------------------------------------------------------
#define BB 512
#define TT 128
#define DD 1024
#define HH 1024
#define VV 256
#define SS 26

typedef _Float16 half8 __attribute__((ext_vector_type(8)));
typedef _Float16 half4 __attribute__((ext_vector_type(4)));
typedef float f32x4 __attribute__((ext_vector_type(4)));

// ---------------------------------------------------------------------------
// async global -> LDS, 16 B per lane. LDS dest must be wave-uniform base +
// lane*16 (it is: all our staging layouts are linear in tid).
// ---------------------------------------------------------------------------
__device__ __forceinline__ void cp16(const void* g, void* l) {
    __builtin_amdgcn_global_load_lds(
        (const __attribute__((address_space(1))) void*)g,
        (__attribute__((address_space(3))) void*)l, 16, 0, 0);
}

// ---------------------------------------------------------------------------
// fast device math
// ---------------------------------------------------------------------------
__device__ __forceinline__ float tanh_fast(float x) {
    float ex = __expf(2.f * x);
    return 1.f - 2.f * __builtin_amdgcn_rcpf(ex + 1.f);
}
__device__ __forceinline__ float sigmoid_fast(float x) {
    return __builtin_amdgcn_rcpf(1.f + __expf(-x));
}

// ---------------------------------------------------------------------------
// f32 -> f16 conversion, 4 elements/thread
// ---------------------------------------------------------------------------
__global__ void cvt_f32_to_f16_v4(const float* __restrict__ src,
                                  _Float16* __restrict__ dst, long n4) {
    long i = (long)blockIdx.x * blockDim.x + threadIdx.x;
    long stride = (long)gridDim.x * blockDim.x;
    for (; i < n4; i += stride) {
        float4 v = ((const float4*)src)[i];
        half4 h;
        h[0] = (_Float16)v.x; h[1] = (_Float16)v.y;
        h[2] = (_Float16)v.z; h[3] = (_Float16)v.w;
        ((half4*)dst)[i] = h;
    }
}

// Gate-interleaved concatenated LSTM weight:
// col c: g=c>>6, q=(c>>4)&3, jl=c&15 -> orig row q*1024+g*16+jl
__global__ void build_wcatp(const float* __restrict__ W_ih,
                            const float* __restrict__ W_hh,
                            _Float16* __restrict__ wcatp) {
    int idx = blockIdx.x * 256 + threadIdx.x;
    int c = idx >> 11;
    int k = idx & 2047;
    int g = c >> 6, q = (c >> 4) & 3, jl = c & 15;
    int row = q * 1024 + g * 16 + jl;
    float v = (k < 1024) ? W_ih[(size_t)row * 1280 + k]
                         : W_hh[(size_t)row * 1024 + (k - 1024)];
    wcatp[idx] = (_Float16)v;
}

// onehT[v][g] = W_ih[g][1024+v]   (fp32, gate-major)
__global__ void build_onehT(const float* __restrict__ W_ih,
                            float* __restrict__ onehT) {
    int idx = blockIdx.x * 256 + threadIdx.x;
    int v = idx >> 12;
    int g = idx & 4095;
    onehT[idx] = W_ih[(size_t)g * 1280 + 1024 + v];
}

__global__ void build_bsum(const float* __restrict__ b_ih,
                           const float* __restrict__ b_hh,
                           float* __restrict__ bsum) {
    int i = blockIdx.x * 256 + threadIdx.x;
    bsum[i] = b_ih[i] + b_hh[i];
}

// ---------------------------------------------------------------------------
// GEMM 128x128: C[M,N] = A[M,K]*B[N,K]^T (+bias). fp16 in, f32 acc.
// Async global->LDS staging (m97 structure).
// MODE 1: f16 out. MODE 2: logits remap (m -> s=m/512,b=m%512) f32 out.
// SWZ 1: XCD row-grouping swizzle (gridDim.y % 8 == 0).
// ---------------------------------------------------------------------------
template <int MODE, int SWZ>
__global__ __launch_bounds__(256) void gemm_bt(
    const _Float16* __restrict__ A, int lda,
    const _Float16* __restrict__ B, int ldb,
    void* __restrict__ Cp, int ldc, int K, const float* __restrict__ bias) {
    __shared__ __align__(16) _Float16 As[128 * 32];
    __shared__ __align__(16) _Float16 Bs[128 * 32];

    int bx = blockIdx.x, by = blockIdx.y;
    if (SWZ) {
        int nx = gridDim.x;
        int bid = by * nx + bx;
        int xcd = bid & 7;
        int local = bid >> 3;
        int rows_per_xcd = gridDim.y >> 3;
        bx = local % nx;
        by = xcd * rows_per_xcd + local / nx;
    }
    const int tid  = threadIdx.x;
    const int lane = tid & 63;
    const int wid  = tid >> 6;
    const int wm   = wid >> 1;
    const int wn   = wid & 1;
    const int m0 = by * 128;
    const int n0 = bx * 128;

    f32x4 acc[4][4];
#pragma unroll
    for (int i = 0; i < 4; ++i)
#pragma unroll
        for (int j = 0; j < 4; ++j)
            acc[i][j] = (f32x4){0.f, 0.f, 0.f, 0.f};

    const int row0 = tid >> 2;
    const int ch0  = tid & 3;
    const _Float16* a0 = A + (size_t)(m0 + row0) * lda + ch0 * 8;
    const _Float16* a1 = A + (size_t)(m0 + row0 + 64) * lda + ch0 * 8;
    const _Float16* b0 = B + (size_t)(n0 + row0) * ldb + ch0 * 8;
    const _Float16* b1 = B + (size_t)(n0 + row0 + 64) * ldb + ch0 * 8;
    _Float16* sa0 = As + tid * 8;            // linear in tid: rows 0..63
    _Float16* sa1 = As + 64 * 32 + tid * 8;  // rows 64..127
    _Float16* sb0 = Bs + tid * 8;
    _Float16* sb1 = Bs + 64 * 32 + tid * 8;

    const int la = lane & 15;
    const int kc = (lane >> 4) * 8;

    for (int k0 = 0; k0 < K; k0 += 32) {
        __syncthreads();           // previous tile fully consumed
        cp16(a0 + k0, sa0);
        cp16(a1 + k0, sa1);
        cp16(b0 + k0, sb0);
        cp16(b1 + k0, sb1);
        __syncthreads();           // barrier drains vmcnt -> tiles ready

        half8 af[4], bf[4];
#pragma unroll
        for (int mt = 0; mt < 4; ++mt)
            af[mt] = *(const half8*)(As + (wm * 64 + mt * 16 + la) * 32 + kc);
#pragma unroll
        for (int nt = 0; nt < 4; ++nt)
            bf[nt] = *(const half8*)(Bs + (wn * 64 + nt * 16 + la) * 32 + kc);
#pragma unroll
        for (int mt = 0; mt < 4; ++mt)
#pragma unroll
            for (int nt = 0; nt < 4; ++nt)
                acc[mt][nt] = __builtin_amdgcn_mfma_f32_16x16x32_f16(
                    af[mt], bf[nt], acc[mt][nt], 0, 0, 0);
    }

#pragma unroll
    for (int mt = 0; mt < 4; ++mt) {
#pragma unroll
        for (int nt = 0; nt < 4; ++nt) {
            int gn = n0 + wn * 64 + nt * 16 + la;
            float bv = bias ? bias[gn] : 0.f;
#pragma unroll
            for (int r = 0; r < 4; ++r) {
                int gm = m0 + wm * 64 + mt * 16 + (lane >> 4) * 4 + r;
                float v = acc[mt][nt][r] + bv;
                if (MODE == 1) {
                    ((_Float16*)Cp)[(size_t)gm * ldc + gn] = (_Float16)v;
                } else {
                    int s = gm >> 9;
                    int b = gm & 511;
                    ((float*)Cp)[((size_t)b * SS + s) * VV + gn] = v;
                }
            }
        }
    }
}

// ---------------------------------------------------------------------------
// GEMM 64x128 core (proj_h and fused-gates). Async staging.
// 4 waves as 2x2; wave = 32 rows x 64 cols = acc[2][4].
// ---------------------------------------------------------------------------
#define GEMM64_CORE(A, lda, B, ldb, K)                                        \
    __shared__ __align__(16) _Float16 As[64 * 32];                            \
    __shared__ __align__(16) _Float16 Bs[128 * 32];                           \
    const int tid  = threadIdx.x;                                             \
    const int lane = tid & 63;                                                \
    const int wid  = tid >> 6;                                                \
    const int wm   = wid >> 1;                                                \
    const int wn   = wid & 1;                                                 \
    const int m0 = blockIdx.y * 64;                                           \
    const int n0 = blockIdx.x * 128;                                          \
    f32x4 acc[2][4];                                                          \
    _Pragma("unroll") for (int i = 0; i < 2; ++i)                             \
        _Pragma("unroll") for (int j = 0; j < 4; ++j)                         \
            acc[i][j] = (f32x4){0.f, 0.f, 0.f, 0.f};                          \
    const int row0 = tid >> 2;                                                \
    const int ch0  = tid & 3;                                                 \
    const _Float16* ag  = A + (size_t)(m0 + row0) * lda + ch0 * 8;            \
    const _Float16* bg0 = B + (size_t)(n0 + row0) * ldb + ch0 * 8;            \
    const _Float16* bg1 = B + (size_t)(n0 + row0 + 64) * ldb + ch0 * 8;       \
    _Float16* sa  = As + tid * 8;                                             \
    _Float16* sb0 = Bs + tid * 8;                                             \
    _Float16* sb1 = Bs + 64 * 32 + tid * 8;                                   \
    const int la = lane & 15;                                                 \
    const int kc = (lane >> 4) * 8;                                           \
    for (int k0 = 0; k0 < K; k0 += 32) {                                      \
        __syncthreads();                                                      \
        cp16(ag + k0, sa);                                                    \
        cp16(bg0 + k0, sb0);                                                  \
        cp16(bg1 + k0, sb1);                                                  \
        __syncthreads();                                                      \
        half8 af[2], bf[4];                                                   \
        _Pragma("unroll") for (int mt = 0; mt < 2; ++mt)                      \
            af[mt] = *(const half8*)(As + (wm * 32 + mt * 16 + la) * 32 + kc);\
        _Pragma("unroll") for (int nt = 0; nt < 4; ++nt)                      \
            bf[nt] = *(const half8*)(Bs + (wn * 64 + nt * 16 + la) * 32 + kc);\
        _Pragma("unroll") for (int mt = 0; mt < 2; ++mt)                      \
            _Pragma("unroll") for (int nt = 0; nt < 4; ++nt)                  \
                acc[mt][nt] = __builtin_amdgcn_mfma_f32_16x16x32_f16(         \
                    af[mt], bf[nt], acc[mt][nt], 0, 0, 0);                    \
    }

// proj_h = h @ h2h^T + b : f32 out
__global__ __launch_bounds__(256) void gemm64_f32(
    const _Float16* __restrict__ A, int lda,
    const _Float16* __restrict__ B, int ldb,
    float* __restrict__ C, int ldc, int K, const float* __restrict__ bias) {
    GEMM64_CORE(A, lda, B, ldb, K)
#pragma unroll
    for (int mt = 0; mt < 2; ++mt)
#pragma unroll
        for (int nt = 0; nt < 4; ++nt) {
            int gn = n0 + wn * 64 + nt * 16 + la;
            float bv = bias[gn];
#pragma unroll
            for (int r = 0; r < 4; ++r) {
                int gm = m0 + wm * 32 + mt * 16 + (lane >> 4) * 4 + r;
                C[(size_t)gm * ldc + gn] = acc[mt][nt][r] + bv;
            }
        }
}

// gates GEMM over gate-interleaved wcatp + fused LSTM pointwise epilogue.
__global__ __launch_bounds__(256) void gemm_gates(
    const _Float16* __restrict__ A,      // acat [B,2048]
    const _Float16* __restrict__ B,      // wcatp [4096,2048]
    const float* __restrict__ bsum,      // [4096] gate-major
    const float* __restrict__ onehT,     // [V,4096] gate-major
    const int* __restrict__ text,        // [B,SS]
    int step,
    float* __restrict__ c,               // [B,H]
    _Float16* __restrict__ acat,         // [B,2048] (h -> cols 1024:2048)
    _Float16* __restrict__ hid) {        // [SS,B,H]
    GEMM64_CORE(A, 2048, B, 2048, 2048)
    const int quad = lane >> 4;
    const int jb = (n0 >> 2) + wn * 16 + la;
    float bs[4];
#pragma unroll
    for (int q = 0; q < 4; ++q) bs[q] = bsum[q * 1024 + jb];
#pragma unroll
    for (int mt = 0; mt < 2; ++mt) {
#pragma unroll
        for (int r = 0; r < 4; ++r) {
            int b = m0 + wm * 32 + mt * 16 + quad * 4 + r;
            int tok = text[b * SS + step];
            const float* orow = onehT + (size_t)tok * 4096;
            float ig = acc[mt][0][r] + bs[0] + orow[jb];
            float fg = acc[mt][1][r] + bs[1] + orow[1024 + jb];
            float gg = acc[mt][2][r] + bs[2] + orow[2048 + jb];
            float og = acc[mt][3][r] + bs[3] + orow[3072 + jb];
            size_t ci = (size_t)b * 1024 + jb;
            float cn = sigmoid_fast(fg) * c[ci] + sigmoid_fast(ig) * tanh_fast(gg);
            float hn = sigmoid_fast(og) * tanh_fast(cn);
            c[ci] = cn;
            _Float16 h16 = (_Float16)hn;
            acat[(size_t)b * 2048 + 1024 + jb] = h16;
            hid[((size_t)step * BB + b) * HH + jb] = h16;
        }
    }
}

// ---------------------------------------------------------------------------
// Fused Bahdanau attention. 512 threads (8 waves) per batch row.
// Phase A: wave wv -> 16 t-rows. Phase C: split over two half-blocks.
// ---------------------------------------------------------------------------
__global__ __launch_bounds__(512) void attn_kernel(
    const _Float16* __restrict__ pH,   // [B,T,H]
    const _Float16* __restrict__ bh,   // [B,T,D]
    const float* __restrict__ ph,      // [B,H]
    const float* __restrict__ sw,      // [H]
    _Float16* __restrict__ acat) {     // [B,2048]
    __shared__ float e_s[TT];
    __shared__ float al_s[TT];
    __shared__ __align__(16) float pc[2][DD];

    const int b = blockIdx.x;
    const int tid = threadIdx.x;
    const int lane = tid & 63;
    const int wv = tid >> 6;

    // register cache of ph and sw for this lane's 16 h's
    float phr[16], swr[16];
    const float4* ph4 = (const float4*)(ph + (size_t)b * HH + lane * 16);
    const float4* sw4 = (const float4*)(sw + lane * 16);
#pragma unroll
    for (int q = 0; q < 4; ++q) {
        float4 t1 = ph4[q];
        phr[q * 4 + 0] = t1.x; phr[q * 4 + 1] = t1.y;
        phr[q * 4 + 2] = t1.z; phr[q * 4 + 3] = t1.w;
        float4 t2 = sw4[q];
        swr[q * 4 + 0] = t2.x; swr[q * 4 + 1] = t2.y;
        swr[q * 4 + 2] = t2.z; swr[q * 4 + 3] = t2.w;
    }

    // Phase A: wave wv handles t = wv*16 .. wv*16+15
    const _Float16* pHb = pH + (size_t)b * TT * HH + lane * 16;
    for (int tt = 0; tt < 16; ++tt) {
        int t = wv * 16 + tt;
        half8 p0 = *(const half8*)(pHb + (size_t)t * HH);
        half8 p1 = *(const half8*)(pHb + (size_t)t * HH + 8);
        float acc = 0.f;
#pragma unroll
        for (int k = 0; k < 8; ++k)
            acc += tanh_fast((float)p0[k] + phr[k]) * swr[k];
#pragma unroll
        for (int k = 0; k < 8; ++k)
            acc += tanh_fast((float)p1[k] + phr[8 + k]) * swr[8 + k];
#pragma unroll
        for (int off = 32; off > 0; off >>= 1) acc += __shfl_xor(acc, off, 64);
        if (lane == 0) e_s[t] = acc;
    }
    __syncthreads();

    // Phase B: softmax over 128 scores
    if (tid < TT) {
        float m = -1e30f;
        for (int t = 0; t < TT; ++t) m = fmaxf(m, e_s[t]);
        float s = 0.f;
        for (int t = 0; t < TT; ++t) s += __expf(e_s[t] - m);
        al_s[tid] = __expf(e_s[tid] - m) / s;
    }
    __syncthreads();

    // Phase C: half-block w2 sums t in [w2*64, w2*64+64); thread owns 4 cols
    const int w2 = tid >> 8;
    const int lc = tid & 255;
    const _Float16* bhb = bh + (size_t)b * TT * DD + lc * 4;
    float c0 = 0.f, c1 = 0.f, c2 = 0.f, c3 = 0.f;
#pragma unroll 4
    for (int t = w2 * 64; t < w2 * 64 + 64; ++t) {
        float a = al_s[t];
        half4 v = *(const half4*)(bhb + (size_t)t * DD);
        c0 += a * (float)v[0];
        c1 += a * (float)v[1];
        c2 += a * (float)v[2];
        c3 += a * (float)v[3];
    }
    ((float4*)pc[w2])[lc] = make_float4(c0, c1, c2, c3);
    __syncthreads();

    if (tid < 256) {
        float4 x0 = ((const float4*)pc[0])[tid];
        float4 x1 = ((const float4*)pc[1])[tid];
        half4 o;
        o[0] = (_Float16)(x0.x + x1.x);
        o[1] = (_Float16)(x0.y + x1.y);
        o[2] = (_Float16)(x0.z + x1.z);
        o[3] = (_Float16)(x0.w + x1.w);
        *(half4*)(acat + (size_t)b * 2048 + tid * 4) = o;
    }
}

// ---------------------------------------------------------------------------
// host
// ---------------------------------------------------------------------------
extern "C" void kernel_launch(void* const* d_in, const int* in_sizes, int n_in,
                              void* d_out, int out_size, void* d_ws, size_t ws_size,
                              hipStream_t stream) {
    const float* batch_H = (const float*)d_in[0];
    const int*   text    = (const int*)d_in[1];
    const float* i2h_w   = (const float*)d_in[2];
    const float* h2h_w   = (const float*)d_in[3];
    const float* h2h_b   = (const float*)d_in[4];
    const float* score_w = (const float*)d_in[5];
    const float* W_ih    = (const float*)d_in[6];
    const float* W_hh    = (const float*)d_in[7];
    const float* b_ih    = (const float*)d_in[8];
    const float* b_hh    = (const float*)d_in[9];
    const float* gen_w   = (const float*)d_in[10];
    const float* gen_b   = (const float*)d_in[11];
    float* out = (float*)d_out;

    char* ws = (char*)d_ws;
    size_t off = 0;
    auto carve = [&](size_t bytes) -> void* {
        void* p = ws + off;
        off += (bytes + 255) & ~(size_t)255;
        return p;
    };
    _Float16* bh16   = (_Float16*)carve((size_t)BB * TT * DD * 2);   // 128 MiB
    _Float16* pH16   = (_Float16*)carve((size_t)BB * TT * HH * 2);   // 128 MiB
    _Float16* wi2h16 = (_Float16*)carve((size_t)HH * DD * 2);
    _Float16* wh2h16 = (_Float16*)carve((size_t)HH * HH * 2);
    _Float16* wcatp  = (_Float16*)carve((size_t)4 * HH * 2048 * 2);  // 16 MiB
    _Float16* wgen16 = (_Float16*)carve((size_t)VV * HH * 2);
    float*    onehT  = (float*)carve((size_t)VV * 4 * HH * 4);       // 4 MiB
    float*    bsum   = (float*)carve((size_t)4 * HH * 4);
    _Float16* acat   = (_Float16*)carve((size_t)BB * 2048 * 2);
    float*    ph_f   = (float*)carve((size_t)BB * HH * 4);
    float*    c_f    = (float*)carve((size_t)BB * HH * 4);
    _Float16* hid16  = (_Float16*)carve((size_t)SS * BB * HH * 2);   // 26 MiB

    const dim3 blk(256);

    cvt_f32_to_f16_v4<<<dim3(16384), blk, 0, stream>>>(batch_H, bh16, (long)BB * TT * DD / 4);
    cvt_f32_to_f16_v4<<<dim3(1024), blk, 0, stream>>>(i2h_w, wi2h16, (long)HH * DD / 4);
    cvt_f32_to_f16_v4<<<dim3(1024), blk, 0, stream>>>(h2h_w, wh2h16, (long)HH * HH / 4);
    cvt_f32_to_f16_v4<<<dim3(256), blk, 0, stream>>>(gen_w, wgen16, (long)VV * HH / 4);
    build_wcatp<<<dim3(4 * HH * 2048 / 256), blk, 0, stream>>>(W_ih, W_hh, wcatp);
    build_onehT<<<dim3(VV * 4 * HH / 256), blk, 0, stream>>>(W_ih, onehT);
    build_bsum<<<dim3(16), blk, 0, stream>>>(b_ih, b_hh, bsum);
    hipMemsetAsync(acat, 0, (size_t)BB * 2048 * 2, stream);  // h0 = 0
    hipMemsetAsync(c_f, 0, (size_t)BB * HH * 4, stream);     // c0 = 0

    // proj_H = batch_H @ i2h_w^T -> f16 [B*T, H], XCD-swizzled
    gemm_bt<1, 1><<<dim3(HH / 128, BB * TT / 128), blk, 0, stream>>>(
        bh16, DD, wi2h16, DD, pH16, HH, DD, nullptr);

    for (int s = 0; s < SS; ++s) {
        // proj_h = h @ h2h^T + h2h_b : [512,1024], grid (8,8)
        gemm64_f32<<<dim3(HH / 128, BB / 64), blk, 0, stream>>>(
            acat + 1024, 2048, wh2h16, HH, ph_f, HH, HH, h2h_b);

        attn_kernel<<<dim3(BB), dim3(512), 0, stream>>>(pH16, bh16, ph_f, score_w, acat);

        // gates GEMM + fused LSTM: [512,2048] x [4096,2048]^T, grid (32,8)
        gemm_gates<<<dim3(4 * HH / 128, BB / 64), blk, 0, stream>>>(
            acat, wcatp, bsum, onehT, text, s, c_f, acat, hid16);
    }

    // logits = hid @ gen_w^T + gen_b, remap [s,b,v] -> [b,s,v]
    gemm_bt<2, 0><<<dim3(VV / 128, SS * BB / 128), blk, 0, stream>>>(
        hid16, HH, wgen16, HH, out, VV, HH, gen_b);
}